// Round 9
// baseline (592.188 us; speedup 1.0000x reference)
//
#include <hip/hip_runtime.h>
#include <stdint.h>

#define NROWS 16384
#define DIM   128
#define VOCAB 8192
#define BN 128
#define BV 64
#define VSPLITS 8
#define SPLITV (VOCAB / VSPLITS)   /* 1024 */
#define NTILES (SPLITV / BV)       /* 16 */
#define MARGIN  0.8f
#define EMB_ELEMS (NROWS * DIM)    /* 2097152 */
#define LIST_CAP_MAX 4194304u
#define LCAP 512

typedef __attribute__((ext_vector_type(8))) short bf16x8;
typedef __attribute__((ext_vector_type(4))) float f32x4;
typedef __attribute__((ext_vector_type(16))) float f32x16;

__device__ __forceinline__ unsigned short f2bf(float f) {
  union { float f; unsigned u; } v; v.f = f;
  unsigned r = v.u + 0x7fffu + ((v.u >> 16) & 1u);
  return (unsigned short)(r >> 16);
}

__device__ __forceinline__ int cvt_pk_bf16(float lo, float hi) {
  int r;
  asm("v_cvt_pk_bf16_f32 %0, %1, %2" : "=v"(r) : "v"(lo), "v"(hi));
  return r;
}

// v_permlane32_swap_b32 a, b:  a' = [a(0:31) | b(0:31)], b' = [a(32:63) | b(32:63)]
__device__ __forceinline__ void permlane_swap(int& a, int& b) {
  asm("v_permlane32_swap_b32 %0, %1" : "+v"(a), "+v"(b));
}

__device__ __forceinline__ bf16x8 pack8(float4 a, float4 b) {
  bf16x8 r;
  r[0] = (short)f2bf(a.x); r[1] = (short)f2bf(a.y);
  r[2] = (short)f2bf(a.z); r[3] = (short)f2bf(a.w);
  r[4] = (short)f2bf(b.x); r[5] = (short)f2bf(b.y);
  r[6] = (short)f2bf(b.z); r[7] = (short)f2bf(b.w);
  return r;
}

// ---------------- prep: c2 = ||c||^2 (fp32), cbf = bf16(codebook) ----------------
__global__ __launch_bounds__(256) void k_prep(const float* __restrict__ cb,
                                              float* __restrict__ c2,
                                              unsigned short* __restrict__ cbf) {
  int tid = threadIdx.x;
  int r = blockIdx.x * 16 + (tid >> 4);
  int l = tid & 15;
  const float* rp = cb + (size_t)r * DIM + l * 8;
  float4 a = *(const float4*)rp;
  float4 b = *(const float4*)(rp + 4);
  float s = a.x*a.x + a.y*a.y + a.z*a.z + a.w*a.w
          + b.x*b.x + b.y*b.y + b.z*b.z + b.w*b.w;
  bf16x8 v8 = pack8(a, b);
  *(bf16x8*)(cbf + (size_t)r * DIM + l * 8) = v8;
#pragma unroll
  for (int o = 1; o < 16; o <<= 1) s += __shfl_xor(s, o);
  if (l == 0) c2[r] = s;
}

// ---------------- transpose: cbfT[d][v] = cbf[v][d] (bf16, 2 MB, one-time) ----------------
__global__ __launch_bounds__(256) void k_tr(const unsigned short* __restrict__ cbf,
                                            unsigned short* __restrict__ cbfT) {
  __shared__ unsigned short t[64][72];
  int vb = blockIdx.x * 64, db = blockIdx.y * 64;
  int tid = threadIdx.x;
#pragma unroll
  for (int ph = 0; ph < 2; ++ph) {
    int r = (tid >> 3) + ph * 32;
    int c = (tid & 7) * 8;
    *(uint4*)&t[r][c] = *(const uint4*)(cbf + (size_t)(vb + r) * DIM + db + c);
  }
  __syncthreads();
#pragma unroll
  for (int ph = 0; ph < 2; ++ph) {
    int d = (tid >> 3) + ph * 32;
    int v8 = (tid & 7) * 8;
    union { uint4 u4; unsigned short s[8]; } val;
#pragma unroll
    for (int k = 0; k < 8; ++k) val.s[k] = t[v8 + k][d];
    *(uint4*)(cbfT + (size_t)(db + d) * VOCAB + vb + v8) = val.u4;
  }
}

// ---------------- main fused kernel (no LDS tiles, no K-loop barriers) ----------------
// Wave w owns m = blockRow + w*32 + (lane&31); lane pair (l, l+32) shares m.
// MFMA1 (32x32x16, swapped): S^T[v][m] = mfma(A=C[v][d], B=X^T[d][m]).
//   sacc[vblk] reg r, lane l: v = vblk*32 + (r&3) + 8*(r>>2) + 4*(l>>5), m = l&31.
// MFMA2: E[m][d] += W[m][v] * C[v][d]; A-frag built via cvt_pk + permlane32_swap;
//   B-frag read from pre-transposed cbfT (global, L2-resident).
__global__ __launch_bounds__(256, 3) void k_main(
    const float* __restrict__ x, const float* __restrict__ c2g,
    const unsigned short* __restrict__ cbf,
    const unsigned short* __restrict__ cbfT,
    float* __restrict__ accum,                  // [NROWS][129] (num | s)
    unsigned int* __restrict__ cnt,
    unsigned int* __restrict__ list, unsigned int cap) {
  __shared__ unsigned int lbuf[LCAP];
  __shared__ unsigned int lcnt;
  __shared__ unsigned int gbase;

  const int tid = threadIdx.x;
  const int lane = tid & 63;
  const int w = tid >> 6;
  const int l31 = lane & 31, h = lane >> 5;
  const int blockRow = blockIdx.x * BN;
  const int vy = blockIdx.y;

  if (tid == 0) lcnt = 0;

  // preload x fragments: lane holds x[m = blockRow+w*32+l31][d = ks*16 + h*8 .. +7]
  bf16x8 afrag[8];
  float x2 = 0.f;
  {
    int gr = blockRow + w * 32 + l31;
    const float* xr = x + (size_t)gr * DIM + h * 8;
#pragma unroll
    for (int ks = 0; ks < 8; ++ks) {
      float4 a = *(const float4*)(xr + ks * 16);
      float4 b = *(const float4*)(xr + ks * 16 + 4);
      x2 += a.x*a.x + a.y*a.y + a.z*a.z + a.w*a.w
          + b.x*b.x + b.y*b.y + b.z*b.z + b.w*b.w;
      afrag[ks] = pack8(a, b);
    }
    x2 += __shfl_xor(x2, 32);   // pair lane holds the other 64 d
  }

  f32x16 eacc[4];
#pragma unroll
  for (int db = 0; db < 4; ++db)
#pragma unroll
    for (int i = 0; i < 16; ++i) eacc[db][i] = 0.f;
  float den = 0.f;
  float runminD = 3.0e19f;

  for (int it = 0; it < NTILES; ++it) {
    const int vbase = vy * SPLITV + it * BV;
    // ---- MFMA 1: S^T = C * X^T, both 32-v blocks, operands from L2 ----
    f32x16 sacc[2];
#pragma unroll
    for (int vblk = 0; vblk < 2; ++vblk) {
#pragma unroll
      for (int i = 0; i < 16; ++i) sacc[vblk][i] = 0.f;
      const unsigned short* arow = cbf + (size_t)(vbase + vblk * 32 + l31) * DIM + h * 8;
#pragma unroll
      for (int ks = 0; ks < 8; ++ks) {
        bf16x8 cf = *(const bf16x8*)(arow + ks * 16);
        sacc[vblk] = __builtin_amdgcn_mfma_f32_32x32x16_bf16(cf, afrag[ks], sacc[vblk], 0, 0, 0);
      }
    }
    // ---- d2 -> dist (in-place into sacc) ----
#pragma unroll
    for (int vblk = 0; vblk < 2; ++vblk) {
#pragma unroll
      for (int g = 0; g < 4; ++g) {
        f32x4 c2f = *(const f32x4*)(c2g + vbase + vblk * 32 + g * 8 + h * 4);
#pragma unroll
        for (int q = 0; q < 4; ++q) {
          int r = g * 4 + q;
          float d2 = fmaxf(fmaf(-2.f, sacc[vblk][r], x2 + c2f[q]), 0.f);
          float dist = sqrtf(d2) + 1e-8f;
          den += dist;
          sacc[vblk][r] = dist;
        }
      }
    }
    // ---- row-min (lane holds 32 of the 64 v for its m; pair has the rest) ----
    float rm = sacc[0][0];
#pragma unroll
    for (int vblk = 0; vblk < 2; ++vblk)
#pragma unroll
      for (int r = 0; r < 16; ++r) rm = fminf(rm, sacc[vblk][r]);
    rm = fminf(rm, __shfl_xor(rm, 32));
    runminD = fminf(runminD, rm);
    float thrD = sqrtf(fmaf(runminD, runminD, MARGIN)) + 2e-8f;
    // ---- emit candidates (gated) ----
    if (__any(rm <= thrD)) {
      unsigned grow = (unsigned)(blockRow + w * 32 + l31);
#pragma unroll
      for (int vblk = 0; vblk < 2; ++vblk)
#pragma unroll
        for (int r = 0; r < 16; ++r) {
          if (sacc[vblk][r] <= thrD) {
            unsigned gv = (unsigned)(vbase + vblk * 32 + (r & 3) + 8 * (r >> 2) + 4 * h);
            unsigned ent = (grow << 13) | gv;
            unsigned pos = atomicAdd(&lcnt, 1u);
            if (pos < LCAP) {
              lbuf[pos] = ent;
            } else {
              unsigned gp = atomicAdd(cnt, 1u);
              if (gp < cap) list[gp] = ent;
            }
          }
        }
    }
    // ---- pack weights + permlane swaps -> A-frags; MFMA2 from cbfT ----
#pragma unroll
    for (int vblk = 0; vblk < 2; ++vblk) {
      int p0 = cvt_pk_bf16(sacc[vblk][0],  sacc[vblk][1]);
      int p1 = cvt_pk_bf16(sacc[vblk][2],  sacc[vblk][3]);
      int p2 = cvt_pk_bf16(sacc[vblk][4],  sacc[vblk][5]);
      int p3 = cvt_pk_bf16(sacc[vblk][6],  sacc[vblk][7]);
      int p4 = cvt_pk_bf16(sacc[vblk][8],  sacc[vblk][9]);
      int p5 = cvt_pk_bf16(sacc[vblk][10], sacc[vblk][11]);
      int p6 = cvt_pk_bf16(sacc[vblk][12], sacc[vblk][13]);
      int p7 = cvt_pk_bf16(sacc[vblk][14], sacc[vblk][15]);
      permlane_swap(p0, p2);   // -> t0.reg0, t0.reg2
      permlane_swap(p1, p3);   // -> t0.reg1, t0.reg3
      permlane_swap(p4, p6);   // -> t1.reg0, t1.reg2
      permlane_swap(p5, p7);   // -> t1.reg1, t1.reg3
#pragma unroll
      for (int t = 0; t < 2; ++t) {
        union { int u[4]; bf16x8 v8; } A;
        A.u[0] = t ? p4 : p0; A.u[1] = t ? p5 : p1;
        A.u[2] = t ? p6 : p2; A.u[3] = t ? p7 : p3;
        int ks = vblk * 2 + t;
        const unsigned short* bcol = cbfT + (size_t)vbase + ks * 16 + h * 8;
#pragma unroll
        for (int dblk = 0; dblk < 4; ++dblk) {
          bf16x8 bw = *(const bf16x8*)(bcol + (size_t)(dblk * 32 + l31) * VOCAB);
          eacc[dblk] = __builtin_amdgcn_mfma_f32_32x32x16_bf16(A.v8, bw, eacc[dblk], 0, 0, 0);
        }
      }
    }
  }
  // ---- flush candidate list: ONE global atomic per block ----
  __syncthreads();
  unsigned total = lcnt < LCAP ? lcnt : LCAP;
  if (tid == 0) gbase = atomicAdd(cnt, total);
  __syncthreads();
  for (unsigned i = tid; i < total; i += 256) {
    unsigned p = gbase + i;
    if (p < cap) list[p] = lbuf[i];
  }
  // ---- flush embed partials: m = (r&3)+8*(r>>2)+4h, d = dblk*32+l31 ----
#pragma unroll
  for (int dblk = 0; dblk < 4; ++dblk) {
#pragma unroll
    for (int r = 0; r < 16; ++r) {
      int grow = blockRow + w * 32 + (r & 3) + 8 * (r >> 2) + 4 * h;
      atomicAdd(&accum[(size_t)grow * 129 + dblk * 32 + l31], eacc[dblk][r]);
    }
  }
  // ---- flush denominator (per m = l31 of this wave; pair lanes sum) ----
  den += __shfl_xor(den, 32);
  if (h == 0)
    atomicAdd(&accum[(size_t)(blockRow + w * 32 + l31) * 129 + 128], den);
}

// ---------------- exact argmin fixup (fp64, one wave per candidate) ----------------
__global__ __launch_bounds__(256) void k_fix(const float* __restrict__ x,
                                             const float* __restrict__ cb,
                                             const unsigned int* __restrict__ list,
                                             const unsigned int* __restrict__ cnt,
                                             unsigned int cap,
                                             unsigned long long* __restrict__ kExact) {
  unsigned n = *cnt; if (n > cap) n = cap;
  int lane = threadIdx.x & 63;
  unsigned wave = blockIdx.x * (blockDim.x >> 6) + (threadIdx.x >> 6);
  unsigned nw = gridDim.x * (blockDim.x >> 6);
  for (unsigned e = wave; e < n; e += nw) {
    unsigned ent = list[e];
    unsigned row = ent >> 13;
    unsigned v = ent & 0x1FFFu;
    const float* xr = x + (size_t)row * DIM;
    const float* cr = cb + (size_t)v * DIM;
    float2 xa = *(const float2*)(xr + lane * 2);
    float2 ca = *(const float2*)(cr + lane * 2);
    double d0 = (double)xa.x - (double)ca.x;
    double d1 = (double)xa.y - (double)ca.y;
    double acc = d0 * d0 + d1 * d1;
    for (int off = 32; off; off >>= 1) acc += __shfl_down(acc, off);
    if (lane == 0)
      atomicMin(&kExact[row],
                ((unsigned long long)__float_as_uint((float)acc) << 32) | (unsigned long long)v);
  }
}

// ---------------- overflow rescue: full exact scan, one wave per row ----------------
__global__ __launch_bounds__(256) void k_rescue(const float* __restrict__ x,
                                                const float* __restrict__ cb,
                                                const unsigned int* __restrict__ cnt,
                                                unsigned int cap,
                                                unsigned long long* __restrict__ kExact) {
  if (*cnt <= cap) return;   // uniform early-out: rescue only needed on list overflow
  __shared__ float xs[4][128];
  int lane = threadIdx.x & 63;
  int wv = threadIdx.x >> 6;
  int row = blockIdx.x * 4 + wv;
  float2 xa = *(const float2*)(x + (size_t)row * DIM + lane * 2);
  xs[wv][lane * 2] = xa.x;
  xs[wv][lane * 2 + 1] = xa.y;
  __syncthreads();
  unsigned long long best = ~0ull;
  for (int v0 = 0; v0 < VOCAB; v0 += 64) {
    int v = v0 + lane;
    const float* cr = cb + (size_t)v * DIM;
    double acc = 0.0;
    for (int d = 0; d < DIM; ++d) {
      double diff = (double)xs[wv][d] - (double)cr[d];
      acc = fma(diff, diff, acc);
    }
    unsigned long long p = ((unsigned long long)__float_as_uint((float)acc) << 32)
                         | (unsigned long long)(unsigned)v;
    best = (p < best) ? p : best;
  }
#pragma unroll
  for (int off = 32; off; off >>= 1) {
    unsigned long long o = __shfl_xor(best, off);
    best = (o < best) ? o : best;
  }
  if (lane == 0) atomicMin(&kExact[row], best);
}

// ---------------- finalize: embed normalize + idx cast (merged) ----------------
__global__ __launch_bounds__(256) void k_out(const float* __restrict__ accum,
                                             const unsigned long long* __restrict__ kExact,
                                             float* __restrict__ out) {
  int i = blockIdx.x * 256 + threadIdx.x;
  if (i < EMB_ELEMS) {
    int row = i >> 7, d = i & 127;
    float s = accum[(size_t)row * 129 + 128];
    out[i] = accum[(size_t)row * 129 + d] / s;
  } else {
    int n = i - EMB_ELEMS;
    out[EMB_ELEMS + n] = (float)(unsigned)(kExact[n] & 0x1FFFu);
  }
}

extern "C" void kernel_launch(void* const* d_in, const int* in_sizes, int n_in,
                              void* d_out, int out_size, void* d_ws, size_t ws_size,
                              hipStream_t stream) {
  const float* x = (const float*)d_in[0];
  const float* cb = (const float*)d_in[1];
  float* out = (float*)d_out;

  char* ws = (char*)d_ws;
  size_t off = 0;
  float* accum = (float*)(ws + off); off += (size_t)NROWS * 129 * 4;
  float* c2 = (float*)(ws + off); off += (size_t)VOCAB * 4;
  unsigned short* cbf = (unsigned short*)(ws + off); off += (size_t)VOCAB * DIM * 2;
  unsigned short* cbfT = (unsigned short*)(ws + off); off += (size_t)VOCAB * DIM * 2;
  unsigned long long* kExact = (unsigned long long*)(ws + off); off += (size_t)NROWS * 8;
  unsigned int* cnt = (unsigned int*)(ws + off); off += 64;
  unsigned int* list = (unsigned int*)(ws + off);
  size_t cap32 = (ws_size > off) ? (ws_size - off) / 4 : 0;
  unsigned cap = (unsigned)(cap32 > LIST_CAP_MAX ? LIST_CAP_MAX : cap32);

  hipMemsetAsync(accum, 0, (size_t)NROWS * 129 * 4, stream);
  hipMemsetAsync(kExact, 0xFF, (size_t)NROWS * 8, stream);
  hipMemsetAsync(cnt, 0, 64, stream);

  k_prep<<<VOCAB / 16, 256, 0, stream>>>(cb, c2, cbf);
  k_tr<<<dim3(VOCAB / 64, DIM / 64), 256, 0, stream>>>(cbf, cbfT);
  k_main<<<dim3(NROWS / BN, VSPLITS), 256, 0, stream>>>(x, c2, cbf, cbfT, accum, cnt, list, cap);
  k_fix<<<1024, 256, 0, stream>>>(x, cb, list, cnt, cap, kExact);
  k_rescue<<<NROWS / 4, 256, 0, stream>>>(x, cb, cnt, cap, kExact);
  k_out<<<(EMB_ELEMS + NROWS) / 256, 256, 0, stream>>>(accum, kExact, out);
}